// Round 18
// baseline (398.307 us; speedup 1.0000x reference)
//
#include <hip/hip_runtime.h>
#include <math.h>

// Problem dims
#define NB    32
#define NC    3
#define NIMG  (NB*NC)      // 96 image-channels
#define NS    384
#define HWSZ  (NS*NS)      // 147456
#define C1OUT 64
#define C1DIM 192
#define PDIM  96
#define PHW   (PDIM*PDIM)  // 9216
#define C2OUT 128
#define KWH   200          // A row stride (padded 193->200: 64B-aligned rows)
#define BHW   192          // stored half-spectrum width in Bh (v = 192..383)
#define PI_F  3.14159265358979323846f

// ---- workspace layout (bytes) ----
// T region @0: twiddle row f2[768], w1p @8192, w2ph @32768, w2pl @180224
// B region @OFF_B: Bh f32[96][384][192] = 28,311,552 + col0 f32[96][384]
// P region @OFF_P: P bf16[16][96][96][64] = 18,874,368 (pooled conv1, chunk-local)
// S region @OFF_S (75,497,472, time-shared):
//   dft phase : A float2[96][384][200] = 58,982,400 (full) / [24] (chunked)
//   conv phase: E bf16[16][192][192][64] = 75,497,472 (full) / [2] (chunked)
// smalls @OFF_SM
static const size_t OFF_T    = 0;
static const size_t OFF_TW1  = 8192;
static const size_t OFF_TW2H = 32768;
static const size_t OFF_TW2L = 180224;
static const size_t OFF_B    = 1179648;
static const size_t OFF_C0   = 1179648 + 28311552;   // col0
static const size_t OFF_P    = 29638656;             // after col0 (147,456)
static const size_t OFF_S    = 57802752;
static const size_t OFF_SM_F = 133300224;
static const size_t OFF_SM_C = 76677120;
static const size_t NEED_F   = 133318912;

// padded LDS index for FFT work arrays: breaks 2^k-stride bank conflicts
#define WI(i) ((i) + ((i) >> 4))

typedef __attribute__((ext_vector_type(8))) short bf16x8_t;
typedef __attribute__((ext_vector_type(4))) float f32x4_t;
union U16 { unsigned u[4]; uint4 q; bf16x8_t v; };

__device__ __forceinline__ float wave_sum(float v){
  #pragma unroll
  for (int off = 32; off; off >>= 1) v += __shfl_down(v, off);
  return v;
}
__device__ __forceinline__ unsigned short f2bf(float f){
  unsigned u = __float_as_uint(f);
  u += 0x7FFFu + ((u >> 16) & 1u);
  return (unsigned short)(u >> 16);
}
__device__ __forceinline__ float bf2f(unsigned short h){
  return __uint_as_float(((unsigned)h) << 16);
}
__device__ __forceinline__ unsigned pmax16(unsigned a, unsigned b){
  unsigned al = a & 0xffffu, ah = a >> 16, bl = b & 0xffffu, bh = b >> 16;
  unsigned ml = al > bl ? al : bl, mh = ah > bh ? ah : bh;
  return (mh << 16) | ml;
}
__device__ __forceinline__ uint4 pmax8(uint4 a, uint4 b){
  uint4 r;
  r.x = pmax16(a.x, b.x); r.y = pmax16(a.y, b.y);
  r.z = pmax16(a.z, b.z); r.w = pmax16(a.w, b.w);
  return r;
}
// proper mod-384 for v in [0, 768): NOT "& 383" (384 not a power of two).
__device__ __forceinline__ int mod384(int v){ return v >= NS ? v - NS : v; }
__device__ __forceinline__ float2 cmul(float2 a, float2 b){
  return make_float2(a.x*b.x - a.y*b.y, a.x*b.y + a.y*b.x);
}

// Merged prep: twiddle row W384^m + conv1 bf16 weight pack + conv2 hi/lo split.
__global__ void k_prep(const float* __restrict__ w1, const float* __restrict__ w2,
    float2* __restrict__ T, unsigned short* __restrict__ w1p,
    unsigned short* __restrict__ w2ph, unsigned short* __restrict__ w2pl){
  int idx = blockIdx.x*256 + (int)threadIdx.x;
  if (idx < NS){
    float ang = -2.0f*PI_F*(float)idx/(float)NS;
    T[NS + idx] = make_float2(cosf(ang), sinf(ang));
  }
  if (idx < 64*192){
    int oc = idx / 192, k = idx - oc*192;
    int rk = k >> 3, kw = k & 7;
    float val = 0.f;
    if (rk < 21 && kw < 7){
      int ic = rk / 7, kh = rk - 7*ic;
      val = w1[oc*147 + ic*49 + kh*7 + kw];
    }
    w1p[idx] = f2bf(val);
  }
  if (idx < 128*576){
    int oc = idx / 576, k = idx - oc*576;
    int tap = k >> 6, ic = k & 63;
    float w = w2[(size_t)oc*576 + ic*9 + tap];
    unsigned short hi = f2bf(w);
    w2ph[idx] = hi;
    w2pl[idx] = f2bf(w - bf2f(hi));
  }
}

// Row FFT (along W, real input): 8 rows/block as 4 packed complex FFTs.
__global__ __launch_bounds__(192) void k_dft_rows(const float* __restrict__ x,
    const float2* __restrict__ T, float2* __restrict__ A,
    float* __restrict__ rgbsum, int bc0){
  __shared__ float2 work[4][408];          // WI(383)=406 max
  __shared__ float rs[3];
  const float2* Trow = T + NS;             // W384^m
  int blk = blockIdx.x;
  int bcl = blk / 48, rg = blk % 48;
  int bc = bc0 + bcl;
  int t = threadIdx.x;
  const float* xp = x + (size_t)bc*HWSZ + (size_t)rg*8*NS;
  int nA = t,        rA = nA % 3, iA = (rA*128) + (__brev((unsigned)(nA/3)) >> 25);
  int nB = t + 192,  rB = nB % 3, iB = (rB*128) + (__brev((unsigned)(nB/3)) >> 25);
  float lsum = 0.f;
  #pragma unroll
  for (int c = 0; c < 4; ++c){
    float a0 = xp[(2*c)*NS + nA],   b0 = xp[(2*c+1)*NS + nA];
    float a1 = xp[(2*c)*NS + nB],   b1 = xp[(2*c+1)*NS + nB];
    work[c][WI(iA)] = make_float2(a0, b0);
    work[c][WI(iB)] = make_float2(a1, b1);
    lsum += a0 + b0 + a1 + b1;
  }
  float ws = wave_sum(lsum);
  if ((t & 63) == 0) rs[t >> 6] = ws;
  __syncthreads();
  if (t == 0) atomicAdd(&rgbsum[bc], rs[0] + rs[1] + rs[2]);

  int sub = t >> 6, j = t & 63;
  #pragma unroll
  for (int st = 0; st < 7; ++st){
    int half = 1 << st;
    int pos = j & (half - 1);
    int ia = sub*128 + (((j >> st) << (st + 1)) | pos);
    int ib = ia + half;
    float2 tw = Trow[(192 >> st) * pos];
    #pragma unroll
    for (int c = 0; c < 4; ++c){
      float2 a = work[c][WI(ia)], b = cmul(work[c][WI(ib)], tw);
      work[c][WI(ia)] = make_float2(a.x + b.x, a.y + b.y);
      work[c][WI(ib)] = make_float2(a.x - b.x, a.y - b.y);
    }
    __syncthreads();
  }
  int k1a = t & 127, k1b = (t + 192) & 127;
  float2 w1 = Trow[t], w2 = Trow[(2*t) % 384];
  float2 Xa[4], Xb[4];
  #pragma unroll
  for (int c = 0; c < 4; ++c){
    float2 p1 = cmul(w1, work[c][WI(128 + k1a)]);
    float2 p2 = cmul(w2, work[c][WI(256 + k1a)]);
    float2 y0 = work[c][WI(k1a)];
    Xa[c] = make_float2(y0.x + p1.x + p2.x, y0.y + p1.y + p2.y);
    float2 q1 = cmul(w1, work[c][WI(128 + k1b)]);
    float2 q2 = cmul(w2, work[c][WI(256 + k1b)]);
    float2 z0 = work[c][WI(k1b)];
    Xb[c] = make_float2(z0.x - q1.x + q2.x, z0.y - q1.y + q2.y);
  }
  __syncthreads();
  #pragma unroll
  for (int c = 0; c < 4; ++c){ work[c][WI(t)] = Xa[c]; work[c][WI(t + 192)] = Xb[c]; }
  __syncthreads();
  int tm = (t == 0) ? 0 : (384 - t);
  #pragma unroll
  for (int c = 0; c < 4; ++c){
    float2 Zk = Xa[c];
    float2 Zm = work[c][WI(tm)];
    size_t b0r = ((size_t)bcl*NS + rg*8 + 2*c)*KWH;
    size_t b1r = b0r + KWH;
    A[b0r + t] = make_float2(0.5f*(Zk.x + Zm.x), 0.5f*(Zk.y - Zm.y));
    A[b1r + t] = make_float2(0.5f*(Zk.y + Zm.y), 0.5f*(Zm.x - Zk.x));
    if (t == 0){
      float2 Zn = Xb[c];
      A[b0r + 192] = make_float2(Zn.x, 0.f);
      A[b1r + 192] = make_float2(Zn.y, 0.f);
    }
  }
}

// Column FFT for kw in [0,192], 8 columns/block. Half-spectrum output (r13).
__global__ __launch_bounds__(192) void k_dft_cols(const float2* __restrict__ A,
    const float2* __restrict__ T, float* __restrict__ Bh, float* __restrict__ col0,
    float* __restrict__ stats, int bc0){
  __shared__ float2 work[8][408];
  __shared__ float rs[6];
  float* mgp = (float*)work;               // overlay after combine: mg[u][c] = mgp[u*9+c]
  const float2* Trow = T + NS;
  int blk = blockIdx.x;
  int bcl = blk / 25, cg = blk % 25;
  int bc = bc0 + bcl;
  int kw0 = cg*8;
  int cols = (cg == 24) ? 1 : 8;
  int t = threadIdx.x;
  const float2* Al = A + (size_t)bcl*NS*KWH;
  if (cols == 8){
    #pragma unroll
    for (int i = 0; i < 16; ++i){
      int lin = i*192 + t;
      int h = lin >> 3, c = lin & 7;
      int r = h % 3;
      work[c][WI(r*128 + (__brev((unsigned)(h/3)) >> 25))] = Al[(size_t)h*KWH + kw0 + c];
    }
  } else {
    for (int h = t; h < NS; h += 192){
      int r = h % 3;
      work[0][WI(r*128 + (__brev((unsigned)(h/3)) >> 25))] = Al[(size_t)h*KWH + kw0];
    }
  }
  __syncthreads();
  int sub = t >> 6, j = t & 63;
  #pragma unroll
  for (int st = 0; st < 7; ++st){
    int half = 1 << st;
    int pos = j & (half - 1);
    int ia = sub*128 + (((j >> st) << (st + 1)) | pos);
    int ib = ia + half;
    float2 tw = Trow[(192 >> st) * pos];
    #pragma unroll
    for (int c = 0; c < 8; ++c){
      if (c < cols){
        float2 a = work[c][WI(ia)], b = cmul(work[c][WI(ib)], tw);
        work[c][WI(ia)] = make_float2(a.x + b.x, a.y + b.y);
        work[c][WI(ib)] = make_float2(a.x - b.x, a.y - b.y);
      }
    }
    __syncthreads();
  }
  int k1a = t & 127, k1b = (t + 192) & 127;
  float2 w1 = Trow[t], w2 = Trow[(2*t) % 384];
  float s1 = 0.f, s2 = 0.f;
  float ma[8], mb[8];
  #pragma unroll
  for (int c = 0; c < 8; ++c){
    ma[c] = 0.f; mb[c] = 0.f;
    if (c < cols){
      float2 p1 = cmul(w1, work[c][WI(128 + k1a)]);
      float2 p2 = cmul(w2, work[c][WI(256 + k1a)]);
      float2 y0 = work[c][WI(k1a)];
      float2 Xa = make_float2(y0.x + p1.x + p2.x, y0.y + p1.y + p2.y);
      float2 q1 = cmul(w1, work[c][WI(128 + k1b)]);
      float2 q2 = cmul(w2, work[c][WI(256 + k1b)]);
      float2 z0 = work[c][WI(k1b)];
      float2 Xb = make_float2(z0.x - q1.x + q2.x, z0.y - q1.y + q2.y);
      ma[c] = logf(sqrtf(Xa.x*Xa.x + Xa.y*Xa.y) + 1.f);   // kh = t     -> u = t+192
      mb[c] = logf(sqrtf(Xb.x*Xb.x + Xb.y*Xb.y) + 1.f);   // kh = t+192 -> u = t
      int kw = kw0 + c;
      float wgt = (kw >= 1 && kw <= 191) ? 2.f : 1.f;
      s1 += wgt*(ma[c] + mb[c]);
      s2 += wgt*(ma[c]*ma[c] + mb[c]*mb[c]);
    }
  }
  __syncthreads();                         // done reading work
  #pragma unroll
  for (int c = 0; c < 8; ++c){
    if (c < cols){
      mgp[(t + 192)*9 + c] = ma[c];
      mgp[t*9 + c]         = mb[c];
    }
  }
  __syncthreads();
  if (cols == 8){
    float* Bhc = Bh + (size_t)bc*NS*BHW;
    #pragma unroll
    for (int rr = 0; rr < 2; ++rr){
      int u = t + rr*192;
      float* row = Bhc + (size_t)u*BHW + kw0;     // j = kw -> v = kw+192
      *(float4*)(row)     = make_float4(mgp[u*9+0], mgp[u*9+1], mgp[u*9+2], mgp[u*9+3]);
      *(float4*)(row + 4) = make_float4(mgp[u*9+4], mgp[u*9+5], mgp[u*9+6], mgp[u*9+7]);
    }
  } else {                                 // kw = 192 -> shifted col v = 0
    float* c0c = col0 + (size_t)bc*NS;
    #pragma unroll
    for (int rr = 0; rr < 2; ++rr){
      int u = t + rr*192;
      c0c[u] = mgp[u*9];
    }
  }
  float w1s = wave_sum(s1), w2s = wave_sum(s2);
  if ((t & 63) == 0){ rs[t >> 6] = w1s; rs[3 + (t >> 6)] = w2s; }
  __syncthreads();
  if (t == 0){
    atomicAdd(&stats[bc*2],     rs[0] + rs[1] + rs[2]);
    atomicAdd(&stats[bc*2 + 1], rs[3] + rs[4] + rs[5]);
  }
}

__global__ void k_finalize(const float* __restrict__ stats, const float* __restrict__ rgbsum,
                           float* __restrict__ ss, float* __restrict__ rgbmean){
  int t = threadIdx.x;
  if (t < NIMG){
    const float inv_n = 1.f / 147456.f;
    float mean = stats[t*2] * inv_n;
    float var  = fmaxf(stats[t*2 + 1] * inv_n - mean*mean, 0.f);
    float inv  = 1.f / (sqrtf(var) + 1e-8f);
    ss[t*2]     = inv;
    ss[t*2 + 1] = -mean * inv;
    rgbmean[t]  = rgbsum[t] * inv_n;
  }
}

// conv1(7x7,s2,p3)+BN+ReLU via MFMA (unchanged from round 15/17).
__global__ __launch_bounds__(256) void k_conv1mfma(const float* __restrict__ Bh,
    const float* __restrict__ col0, const float* __restrict__ ss,
    const unsigned short* __restrict__ w1p, const float* __restrict__ b1,
    const float* __restrict__ g1, const float* __restrict__ bb1,
    unsigned short* __restrict__ E, int b0){
  __shared__ unsigned short pt[3*37*40];
  int blk = blockIdx.x;
  int li = blk / 144, rem = blk - li*144;
  int rg = rem / 12, cg = rem - rg*12;
  int r0 = rg*16, c0 = cg*16;
  int b = b0 + li;
  int t = threadIdx.x;
  float sc[3], sh[3];
  #pragma unroll
  for (int ic = 0; ic < 3; ++ic){ sc[ic] = ss[(b*3 + ic)*2]; sh[ic] = ss[(b*3 + ic)*2 + 1]; }
  const int h0 = 2*r0 - 3, w0 = 2*c0 - 3;
  for (int lin = t; lin < 3*37*40; lin += 256){
    int ic = lin / 1480; int r = lin - ic*1480;
    int hr = r / 40, wc = r - hr*40;
    int hg = h0 + hr, wg = w0 + wc;
    bool v = (wc < 38) && ((unsigned)hg < (unsigned)NS) && ((unsigned)wg < (unsigned)NS);
    float raw = 0.f;
    if (v){
      const float* Bc = Bh + (size_t)(b*3 + ic)*NS*BHW;
      if (wg >= 192)      raw = Bc[(size_t)hg*BHW + (wg - 192)];
      else if (wg >= 1)   raw = Bc[(size_t)mod384(NS - hg)*BHW + (192 - wg)];
      else                raw = col0[(size_t)(b*3 + ic)*NS + hg];
    }
    pt[lin] = v ? f2bf(fmaf(raw, sc[ic], sh[ic])) : (unsigned short)0;
  }
  __syncthreads();

  int wave = t >> 6, lane = t & 63;
  int lm = lane & 15, lg = lane >> 4;
  U16 bf[6];
  #pragma unroll
  for (int ks = 0; ks < 6; ++ks)
    bf[ks].q = *(const uint4*)(w1p + (wave*16 + lm)*192 + ks*32 + lg*8);
  int cbase[6];
  #pragma unroll
  for (int ks = 0; ks < 6; ++ks){
    int rk = ks*4 + lg;
    if (rk > 20) rk = 20;
    int ic = rk / 7, kh = rk - 7*ic;
    cbase[ks] = ic*1480 + kh*40 + 2*lm;
  }
  const float bneps = rsqrtf(1.f + 1e-5f);
  float4 b4  = *(const float4*)(b1  + wave*16 + lg*4);
  float4 g4  = *(const float4*)(g1  + wave*16 + lg*4);
  float4 bb4 = *(const float4*)(bb1 + wave*16 + lg*4);
  float4 gs4 = make_float4(g4.x*bneps, g4.y*bneps, g4.z*bneps, g4.w*bneps);
  unsigned short* Eb = E + (((size_t)li*C1DIM + r0)*C1DIM + c0 + lm)*64 + wave*16 + lg*4;

  #pragma unroll 1
  for (int rt = 0; rt < 16; ++rt){
    f32x4_t acc = {b4.x, b4.y, b4.z, b4.w};
    #pragma unroll
    for (int ks = 0; ks < 6; ++ks){
      U16 a;
      const unsigned* pp = (const unsigned*)&pt[cbase[ks] + 80*rt];
      a.u[0] = pp[0]; a.u[1] = pp[1]; a.u[2] = pp[2]; a.u[3] = pp[3];
      acc = __builtin_amdgcn_mfma_f32_16x16x32_bf16(bf[ks].v, a.v, acc, 0, 0, 0);
    }
    ushort4 o;
    o.x = f2bf(fmaxf(fmaf(acc[0], gs4.x, bb4.x), 0.f));
    o.y = f2bf(fmaxf(fmaf(acc[1], gs4.y, bb4.y), 0.f));
    o.z = f2bf(fmaxf(fmaf(acc[2], gs4.z, bb4.z), 0.f));
    o.w = f2bf(fmaxf(fmaf(acc[3], gs4.w, bb4.w), 0.f));
    *(ushort4*)(Eb + (size_t)rt*C1DIM*64) = o;
  }
}

// maxpool 3x3 s2 p1 over E -> P bf16[cvB][96][96][64] (unchanged from r15).
__global__ __launch_bounds__(256) void k_pool(const unsigned short* __restrict__ E,
    unsigned short* __restrict__ P){
  int lin = blockIdx.x*256 + (int)threadIdx.x;   // ((li*96+ph)*96+pw)*8+g
  int g = lin & 7; int rm = lin >> 3;
  int pw = rm % PDIM; int rm2 = rm / PDIM;
  int ph = rm2 % PDIM; int li = rm2 / PDIM;
  const unsigned short* Eb = E + (size_t)li*C1DIM*C1DIM*64 + g*8;
  uint4 mx = make_uint4(0u,0u,0u,0u);
  #pragma unroll
  for (int dh = 0; dh < 3; ++dh){
    int eh = 2*ph - 1 + dh;
    if ((unsigned)eh >= (unsigned)C1DIM) continue;
    #pragma unroll
    for (int dw = 0; dw < 3; ++dw){
      int ew = 2*pw - 1 + dw;
      if ((unsigned)ew >= (unsigned)C1DIM) continue;
      mx = pmax8(mx, *(const uint4*)(Eb + ((size_t)eh*C1DIM + ew)*64));
    }
  }
  *(uint4*)(P + ((size_t)rm)*64 + g*8) = mx;
}

// conv2(3x3,p1)+BN+ReLU + global-avg-pool via MFMA.
// Round-18 mapping: SAME block tile (8x16 pos x 128 oc, 23KB sD, FETCH
// unchanged) but 4 waves x 32 oc instead of 8 waves x 16 oc: each data
// fragment read from LDS feeds 4 MFMAs (2 oc-tiles x hi/lo) -> block LDS
// traffic HALVED (r17 diagnosis: LDS stream was the top pipe at 24 us).
// Weight stream per block unchanged (waves own distinct oc). Arithmetic
// sequence per output identical to r15/r17 -> absmax unchanged.
__global__ __launch_bounds__(256) void k_conv2mfma(const unsigned short* __restrict__ P,
    const unsigned short* __restrict__ w2ph, const unsigned short* __restrict__ w2pl,
    const float* __restrict__ b2, const float* __restrict__ g2,
    const float* __restrict__ bb2, float* __restrict__ freq_acc, int b0){
  __shared__ unsigned short sD[10*1152];   // [hp(10)][g(8)][wp(18)][8ic]
  int blk = blockIdx.x;
  int li = blk / 72, tile = blk - li*72;
  int rb = tile / 6, cb = tile - rb*6;
  int r0 = rb*8, c0 = cb*16;
  int b = b0 + li;
  int t = threadIdx.x;
  const unsigned short* Pb = P + (size_t)li*PHW*64;
  for (int lin = t; lin < 1440; lin += 256){
    int g = lin & 7; int rm = lin >> 3;
    int wp = rm % 18, hp = rm / 18;
    int ph = r0 + hp - 1, pw = c0 + wp - 1;
    uint4 v = make_uint4(0u,0u,0u,0u);
    if ((unsigned)ph < (unsigned)PDIM && (unsigned)pw < (unsigned)PDIM)
      v = *(const uint4*)(Pb + ((size_t)ph*PDIM + pw)*64 + g*8);
    *(uint4*)&sD[hp*1152 + g*144 + wp*8] = v;
  }
  __syncthreads();

  int wave = t >> 6, lane = t & 63;
  int lm = lane & 15, lg = lane >> 4;
  int ocbase = wave*32;                    // 4 waves x 32 oc
  const float bneps = rsqrtf(1.f + 1e-5f);
  float4 b4A  = *(const float4*)(b2  + ocbase + lg*4);
  float4 g4A  = *(const float4*)(g2  + ocbase + lg*4);
  float4 bb4A = *(const float4*)(bb2 + ocbase + lg*4);
  float4 b4B  = *(const float4*)(b2  + ocbase + 16 + lg*4);
  float4 g4B  = *(const float4*)(g2  + ocbase + 16 + lg*4);
  float4 bb4B = *(const float4*)(bb2 + ocbase + 16 + lg*4);
  f32x4_t accA[8], accB[8];
  #pragma unroll
  for (int nt = 0; nt < 8; ++nt){
    accA[nt][0] = b4A.x; accA[nt][1] = b4A.y; accA[nt][2] = b4A.z; accA[nt][3] = b4A.w;
    accB[nt][0] = b4B.x; accB[nt][1] = b4B.y; accB[nt][2] = b4B.z; accB[nt][3] = b4B.w;
  }
  const unsigned short* whpA = w2ph + (size_t)(ocbase + lm)*576;
  const unsigned short* wlpA = w2pl + (size_t)(ocbase + lm)*576;
  const unsigned short* whpB = w2ph + (size_t)(ocbase + 16 + lm)*576;
  const unsigned short* wlpB = w2pl + (size_t)(ocbase + 16 + lm)*576;
  #pragma unroll
  for (int ks = 0; ks < 18; ++ks){
    const int tap = ks >> 1, h32 = ks & 1;
    const int dh = tap / 3, dw = tap - 3*(tap/3);
    U16 whA, wlA, whB, wlB;
    whA.q = *(const uint4*)(whpA + ks*32 + lg*8);
    wlA.q = *(const uint4*)(wlpA + ks*32 + lg*8);
    whB.q = *(const uint4*)(whpB + ks*32 + lg*8);
    wlB.q = *(const uint4*)(wlpB + ks*32 + lg*8);
    int base = (h32*4 + lg)*144 + (lm + dw)*8;
    #pragma unroll
    for (int nt = 0; nt < 8; ++nt){
      U16 a;
      a.q = *(const uint4*)&sD[(nt + dh)*1152 + base];
      accA[nt] = __builtin_amdgcn_mfma_f32_16x16x32_bf16(whA.v, a.v, accA[nt], 0, 0, 0);
      accA[nt] = __builtin_amdgcn_mfma_f32_16x16x32_bf16(wlA.v, a.v, accA[nt], 0, 0, 0);
      accB[nt] = __builtin_amdgcn_mfma_f32_16x16x32_bf16(whB.v, a.v, accB[nt], 0, 0, 0);
      accB[nt] = __builtin_amdgcn_mfma_f32_16x16x32_bf16(wlB.v, a.v, accB[nt], 0, 0, 0);
    }
  }
  // BN+ReLU + pool-sum for both oc-tiles
  {
    float s0 = 0.f, s1 = 0.f, s2 = 0.f, s3 = 0.f;
    float gx = g4A.x*bneps, gy = g4A.y*bneps, gz = g4A.z*bneps, gw = g4A.w*bneps;
    #pragma unroll
    for (int nt = 0; nt < 8; ++nt){
      s0 += fmaxf(fmaf(accA[nt][0], gx, bb4A.x), 0.f);
      s1 += fmaxf(fmaf(accA[nt][1], gy, bb4A.y), 0.f);
      s2 += fmaxf(fmaf(accA[nt][2], gz, bb4A.z), 0.f);
      s3 += fmaxf(fmaf(accA[nt][3], gw, bb4A.w), 0.f);
    }
    #pragma unroll
    for (int off = 1; off < 16; off <<= 1){
      s0 += __shfl_xor(s0, off);
      s1 += __shfl_xor(s1, off);
      s2 += __shfl_xor(s2, off);
      s3 += __shfl_xor(s3, off);
    }
    if (lm == 0){
      float* fa = freq_acc + (size_t)b*C2OUT + ocbase + lg*4;
      atomicAdd(fa + 0, s0); atomicAdd(fa + 1, s1);
      atomicAdd(fa + 2, s2); atomicAdd(fa + 3, s3);
    }
  }
  {
    float s0 = 0.f, s1 = 0.f, s2 = 0.f, s3 = 0.f;
    float gx = g4B.x*bneps, gy = g4B.y*bneps, gz = g4B.z*bneps, gw = g4B.w*bneps;
    #pragma unroll
    for (int nt = 0; nt < 8; ++nt){
      s0 += fmaxf(fmaf(accB[nt][0], gx, bb4B.x), 0.f);
      s1 += fmaxf(fmaf(accB[nt][1], gy, bb4B.y), 0.f);
      s2 += fmaxf(fmaf(accB[nt][2], gz, bb4B.z), 0.f);
      s3 += fmaxf(fmaf(accB[nt][3], gw, bb4B.w), 0.f);
    }
    #pragma unroll
    for (int off = 1; off < 16; off <<= 1){
      s0 += __shfl_xor(s0, off);
      s1 += __shfl_xor(s1, off);
      s2 += __shfl_xor(s2, off);
      s3 += __shfl_xor(s3, off);
    }
    if (lm == 0){
      float* fa = freq_acc + (size_t)b*C2OUT + ocbase + 16 + lg*4;
      atomicAdd(fa + 0, s0); atomicAdd(fa + 1, s1);
      atomicAdd(fa + 2, s2); atomicAdd(fa + 3, s3);
    }
  }
}

// RGB head + concat + 3-layer MLP, one block per batch sample.
__global__ __launch_bounds__(256) void k_mlp(const float* __restrict__ rgbmean,
    const float* __restrict__ freq_acc, const float* __restrict__ w_rgb,
    const float* __restrict__ b_rgb, const float* __restrict__ fc1w,
    const float* __restrict__ fc1b, const float* __restrict__ fc2w,
    const float* __restrict__ fc2b, const float* __restrict__ fc3w,
    const float* __restrict__ fc3b, float* __restrict__ out){
  __shared__ float z[130], z1[256], z2[128];
  int b = blockIdx.x, t = threadIdx.x;
  if (t < 2){
    float s = b_rgb[t];
    #pragma unroll
    for (int c = 0; c < 3; ++c) s += rgbmean[b*3 + c] * w_rgb[c*2 + t];
    z[t] = s;
  }
  if (t < 128) z[2 + t] = freq_acc[b*C2OUT + t] * (1.f/9216.f);
  __syncthreads();
  { float s = fc1b[t];
    for (int k = 0; k < 130; ++k) s = fmaf(z[k], fc1w[k*256 + t], s);
    z1[t] = fmaxf(s, 0.f); }
  __syncthreads();
  if (t < 128){
    float s = fc2b[t];
    for (int k = 0; k < 256; ++k) s = fmaf(z1[k], fc2w[k*128 + t], s);
    z2[t] = fmaxf(s, 0.f); }
  __syncthreads();
  if (t < 2){
    float s = fc3b[t];
    for (int k = 0; k < 128; ++k) s = fmaf(z2[k], fc3w[k*2 + t], s);
    out[b*2 + t] = s; }
}

extern "C" void kernel_launch(void* const* d_in, const int* in_sizes, int n_in,
                              void* d_out, int out_size, void* d_ws, size_t ws_size,
                              hipStream_t stream){
  const float* x     = (const float*)d_in[0];
  const float* w_rgb = (const float*)d_in[1];
  const float* b_rgb = (const float*)d_in[2];
  const float* w1    = (const float*)d_in[3];
  const float* b1    = (const float*)d_in[4];
  const float* g1    = (const float*)d_in[5];
  const float* bb1   = (const float*)d_in[6];
  const float* w2    = (const float*)d_in[7];
  const float* b2    = (const float*)d_in[8];
  const float* g2    = (const float*)d_in[9];
  const float* bb2   = (const float*)d_in[10];
  const float* fc1w  = (const float*)d_in[11];
  const float* fc1b  = (const float*)d_in[12];
  const float* fc2w  = (const float*)d_in[13];
  const float* fc2b  = (const float*)d_in[14];
  const float* fc3w  = (const float*)d_in[15];
  const float* fc3b  = (const float*)d_in[16];

  const bool full = (ws_size >= NEED_F);
  const int dftloop = full ? 1 : 4;
  const int dftCH   = full ? 96 : 24;
  const int cvloop  = full ? 2 : 16;
  const int cvB     = full ? 16 : 2;

  char* ws = (char*)d_ws;
  float2* T  = (float2*)(ws + OFF_T);
  unsigned short* w1p  = (unsigned short*)(ws + OFF_TW1);
  unsigned short* w2ph = (unsigned short*)(ws + OFF_TW2H);
  unsigned short* w2pl = (unsigned short*)(ws + OFF_TW2L);
  float*  Bh   = (float*)(ws + OFF_B);
  float*  col0 = (float*)(ws + OFF_C0);
  unsigned short* P = (unsigned short*)(ws + OFF_P);
  float2* A    = (float2*)(ws + OFF_S);
  unsigned short* E = (unsigned short*)(ws + OFF_S);
  float*  sm = (float*)(ws + (full ? OFF_SM_F : OFF_SM_C));
  float* rgbsum = sm;            // 96
  float* stats  = sm + 96;       // 192
  float* freqa  = sm + 288;      // 4096
  float* rgbm   = sm + 4384;     // 96
  float* ssb    = sm + 4480;     // 192

  hipMemsetAsync(sm, 0, 4672*sizeof(float), stream);
  k_prep<<<288, 256, 0, stream>>>(w1, w2, T, w1p, w2ph, w2pl);
  for (int c = 0; c < dftloop; ++c){
    k_dft_rows<<<dftCH*48, 192, 0, stream>>>(x, T, A, rgbsum, c*dftCH);
    k_dft_cols<<<dftCH*25, 192, 0, stream>>>(A, T, Bh, col0, stats, c*dftCH);
  }
  k_finalize<<<1, 128, 0, stream>>>(stats, rgbsum, ssb, rgbm);
  for (int c = 0; c < cvloop; ++c){
    k_conv1mfma<<<cvB*144, 256, 0, stream>>>(Bh, col0, ssb, w1p, b1, g1, bb1, E, c*cvB);
    k_pool<<<cvB*288, 256, 0, stream>>>(E, P);
    k_conv2mfma<<<cvB*72, 256, 0, stream>>>(P, w2ph, w2pl, b2, g2, bb2, freqa, c*cvB);
  }
  k_mlp<<<NB, 256, 0, stream>>>(rgbm, freqa, w_rgb, b_rgb, fc1w, fc1b,
                                fc2w, fc2b, fc3w, fc3b, (float*)d_out);
}

// Round 19
// 388.005 us; speedup vs baseline: 1.0266x; 1.0266x over previous
//
#include <hip/hip_runtime.h>
#include <math.h>

// Problem dims
#define NB    32
#define NC    3
#define NIMG  (NB*NC)      // 96 image-channels
#define NS    384
#define HWSZ  (NS*NS)      // 147456
#define C1OUT 64
#define C1DIM 192
#define PDIM  96
#define PHW   (PDIM*PDIM)  // 9216
#define C2OUT 128
#define KWH   200          // A row stride (padded 193->200: 64B-aligned rows)
#define BHW   192          // stored half-spectrum width in Bh (v = 192..383)
#define PI_F  3.14159265358979323846f

// ---- workspace layout (bytes) ----
// T region @0: twiddle row f2[768], w1p @8192, w2ph @32768, w2pl @180224
// B region @OFF_B: Bh f32[96][384][192] = 28,311,552 + col0 f32[96][384]
// P region @OFF_P: P bf16[16][96][96][64] = 18,874,368 (pooled conv1, chunk-local)
// S region @OFF_S (75,497,472, time-shared):
//   dft phase : A float2[96][384][200] = 58,982,400 (full) / [24] (chunked)
//   conv phase: E bf16[16][192][192][64] = 75,497,472 (full) / [2] (chunked)
// smalls @OFF_SM
static const size_t OFF_T    = 0;
static const size_t OFF_TW1  = 8192;
static const size_t OFF_TW2H = 32768;
static const size_t OFF_TW2L = 180224;
static const size_t OFF_B    = 1179648;
static const size_t OFF_C0   = 1179648 + 28311552;   // col0
static const size_t OFF_P    = 29638656;             // after col0 (147,456)
static const size_t OFF_S    = 57802752;
static const size_t OFF_SM_F = 133300224;
static const size_t OFF_SM_C = 76677120;
static const size_t NEED_F   = 133318912;

// padded LDS index for FFT work arrays: breaks 2^k-stride bank conflicts
#define WI(i) ((i) + ((i) >> 4))

typedef __attribute__((ext_vector_type(8))) short bf16x8_t;
typedef __attribute__((ext_vector_type(4))) float f32x4_t;
union U16 { unsigned u[4]; uint4 q; bf16x8_t v; };

__device__ __forceinline__ float wave_sum(float v){
  #pragma unroll
  for (int off = 32; off; off >>= 1) v += __shfl_down(v, off);
  return v;
}
__device__ __forceinline__ unsigned short f2bf(float f){
  unsigned u = __float_as_uint(f);
  u += 0x7FFFu + ((u >> 16) & 1u);
  return (unsigned short)(u >> 16);
}
__device__ __forceinline__ float bf2f(unsigned short h){
  return __uint_as_float(((unsigned)h) << 16);
}
__device__ __forceinline__ unsigned pmax16(unsigned a, unsigned b){
  unsigned al = a & 0xffffu, ah = a >> 16, bl = b & 0xffffu, bh = b >> 16;
  unsigned ml = al > bl ? al : bl, mh = ah > bh ? ah : bh;
  return (mh << 16) | ml;
}
__device__ __forceinline__ uint4 pmax8(uint4 a, uint4 b){
  uint4 r;
  r.x = pmax16(a.x, b.x); r.y = pmax16(a.y, b.y);
  r.z = pmax16(a.z, b.z); r.w = pmax16(a.w, b.w);
  return r;
}
// proper mod-384 for v in [0, 768): NOT "& 383" (384 not a power of two).
__device__ __forceinline__ int mod384(int v){ return v >= NS ? v - NS : v; }
__device__ __forceinline__ float2 cmul(float2 a, float2 b){
  return make_float2(a.x*b.x - a.y*b.y, a.x*b.y + a.y*b.x);
}

// Merged prep: twiddle row W384^m + conv1 bf16 weight pack + conv2 hi/lo split.
__global__ void k_prep(const float* __restrict__ w1, const float* __restrict__ w2,
    float2* __restrict__ T, unsigned short* __restrict__ w1p,
    unsigned short* __restrict__ w2ph, unsigned short* __restrict__ w2pl){
  int idx = blockIdx.x*256 + (int)threadIdx.x;
  if (idx < NS){
    float ang = -2.0f*PI_F*(float)idx/(float)NS;
    T[NS + idx] = make_float2(cosf(ang), sinf(ang));
  }
  if (idx < 64*192){
    int oc = idx / 192, k = idx - oc*192;
    int rk = k >> 3, kw = k & 7;
    float val = 0.f;
    if (rk < 21 && kw < 7){
      int ic = rk / 7, kh = rk - 7*ic;
      val = w1[oc*147 + ic*49 + kh*7 + kw];
    }
    w1p[idx] = f2bf(val);
  }
  if (idx < 128*576){
    int oc = idx / 576, k = idx - oc*576;
    int tap = k >> 6, ic = k & 63;
    float w = w2[(size_t)oc*576 + ic*9 + tap];
    unsigned short hi = f2bf(w);
    w2ph[idx] = hi;
    w2pl[idx] = f2bf(w - bf2f(hi));
  }
}

// Row FFT (along W, real input): 8 rows/block as 4 packed complex FFTs.
__global__ __launch_bounds__(192) void k_dft_rows(const float* __restrict__ x,
    const float2* __restrict__ T, float2* __restrict__ A,
    float* __restrict__ rgbsum, int bc0){
  __shared__ float2 work[4][408];          // WI(383)=406 max
  __shared__ float rs[3];
  const float2* Trow = T + NS;             // W384^m
  int blk = blockIdx.x;
  int bcl = blk / 48, rg = blk % 48;
  int bc = bc0 + bcl;
  int t = threadIdx.x;
  const float* xp = x + (size_t)bc*HWSZ + (size_t)rg*8*NS;
  int nA = t,        rA = nA % 3, iA = (rA*128) + (__brev((unsigned)(nA/3)) >> 25);
  int nB = t + 192,  rB = nB % 3, iB = (rB*128) + (__brev((unsigned)(nB/3)) >> 25);
  float lsum = 0.f;
  #pragma unroll
  for (int c = 0; c < 4; ++c){
    float a0 = xp[(2*c)*NS + nA],   b0 = xp[(2*c+1)*NS + nA];
    float a1 = xp[(2*c)*NS + nB],   b1 = xp[(2*c+1)*NS + nB];
    work[c][WI(iA)] = make_float2(a0, b0);
    work[c][WI(iB)] = make_float2(a1, b1);
    lsum += a0 + b0 + a1 + b1;
  }
  float ws = wave_sum(lsum);
  if ((t & 63) == 0) rs[t >> 6] = ws;
  __syncthreads();
  if (t == 0) atomicAdd(&rgbsum[bc], rs[0] + rs[1] + rs[2]);

  int sub = t >> 6, j = t & 63;
  #pragma unroll
  for (int st = 0; st < 7; ++st){
    int half = 1 << st;
    int pos = j & (half - 1);
    int ia = sub*128 + (((j >> st) << (st + 1)) | pos);
    int ib = ia + half;
    float2 tw = Trow[(192 >> st) * pos];
    #pragma unroll
    for (int c = 0; c < 4; ++c){
      float2 a = work[c][WI(ia)], b = cmul(work[c][WI(ib)], tw);
      work[c][WI(ia)] = make_float2(a.x + b.x, a.y + b.y);
      work[c][WI(ib)] = make_float2(a.x - b.x, a.y - b.y);
    }
    __syncthreads();
  }
  int k1a = t & 127, k1b = (t + 192) & 127;
  float2 w1 = Trow[t], w2 = Trow[(2*t) % 384];
  float2 Xa[4], Xb[4];
  #pragma unroll
  for (int c = 0; c < 4; ++c){
    float2 p1 = cmul(w1, work[c][WI(128 + k1a)]);
    float2 p2 = cmul(w2, work[c][WI(256 + k1a)]);
    float2 y0 = work[c][WI(k1a)];
    Xa[c] = make_float2(y0.x + p1.x + p2.x, y0.y + p1.y + p2.y);
    float2 q1 = cmul(w1, work[c][WI(128 + k1b)]);
    float2 q2 = cmul(w2, work[c][WI(256 + k1b)]);
    float2 z0 = work[c][WI(k1b)];
    Xb[c] = make_float2(z0.x - q1.x + q2.x, z0.y - q1.y + q2.y);
  }
  __syncthreads();
  #pragma unroll
  for (int c = 0; c < 4; ++c){ work[c][WI(t)] = Xa[c]; work[c][WI(t + 192)] = Xb[c]; }
  __syncthreads();
  int tm = (t == 0) ? 0 : (384 - t);
  #pragma unroll
  for (int c = 0; c < 4; ++c){
    float2 Zk = Xa[c];
    float2 Zm = work[c][WI(tm)];
    size_t b0r = ((size_t)bcl*NS + rg*8 + 2*c)*KWH;
    size_t b1r = b0r + KWH;
    A[b0r + t] = make_float2(0.5f*(Zk.x + Zm.x), 0.5f*(Zk.y - Zm.y));
    A[b1r + t] = make_float2(0.5f*(Zk.y + Zm.y), 0.5f*(Zm.x - Zk.x));
    if (t == 0){
      float2 Zn = Xb[c];
      A[b0r + 192] = make_float2(Zn.x, 0.f);
      A[b1r + 192] = make_float2(Zn.y, 0.f);
    }
  }
}

// Column FFT for kw in [0,192], 8 columns/block. Half-spectrum output (r13).
__global__ __launch_bounds__(192) void k_dft_cols(const float2* __restrict__ A,
    const float2* __restrict__ T, float* __restrict__ Bh, float* __restrict__ col0,
    float* __restrict__ stats, int bc0){
  __shared__ float2 work[8][408];
  __shared__ float rs[6];
  float* mgp = (float*)work;               // overlay after combine: mg[u][c] = mgp[u*9+c]
  const float2* Trow = T + NS;
  int blk = blockIdx.x;
  int bcl = blk / 25, cg = blk % 25;
  int bc = bc0 + bcl;
  int kw0 = cg*8;
  int cols = (cg == 24) ? 1 : 8;
  int t = threadIdx.x;
  const float2* Al = A + (size_t)bcl*NS*KWH;
  if (cols == 8){
    #pragma unroll
    for (int i = 0; i < 16; ++i){
      int lin = i*192 + t;
      int h = lin >> 3, c = lin & 7;
      int r = h % 3;
      work[c][WI(r*128 + (__brev((unsigned)(h/3)) >> 25))] = Al[(size_t)h*KWH + kw0 + c];
    }
  } else {
    for (int h = t; h < NS; h += 192){
      int r = h % 3;
      work[0][WI(r*128 + (__brev((unsigned)(h/3)) >> 25))] = Al[(size_t)h*KWH + kw0];
    }
  }
  __syncthreads();
  int sub = t >> 6, j = t & 63;
  #pragma unroll
  for (int st = 0; st < 7; ++st){
    int half = 1 << st;
    int pos = j & (half - 1);
    int ia = sub*128 + (((j >> st) << (st + 1)) | pos);
    int ib = ia + half;
    float2 tw = Trow[(192 >> st) * pos];
    #pragma unroll
    for (int c = 0; c < 8; ++c){
      if (c < cols){
        float2 a = work[c][WI(ia)], b = cmul(work[c][WI(ib)], tw);
        work[c][WI(ia)] = make_float2(a.x + b.x, a.y + b.y);
        work[c][WI(ib)] = make_float2(a.x - b.x, a.y - b.y);
      }
    }
    __syncthreads();
  }
  int k1a = t & 127, k1b = (t + 192) & 127;
  float2 w1 = Trow[t], w2 = Trow[(2*t) % 384];
  float s1 = 0.f, s2 = 0.f;
  float ma[8], mb[8];
  #pragma unroll
  for (int c = 0; c < 8; ++c){
    ma[c] = 0.f; mb[c] = 0.f;
    if (c < cols){
      float2 p1 = cmul(w1, work[c][WI(128 + k1a)]);
      float2 p2 = cmul(w2, work[c][WI(256 + k1a)]);
      float2 y0 = work[c][WI(k1a)];
      float2 Xa = make_float2(y0.x + p1.x + p2.x, y0.y + p1.y + p2.y);
      float2 q1 = cmul(w1, work[c][WI(128 + k1b)]);
      float2 q2 = cmul(w2, work[c][WI(256 + k1b)]);
      float2 z0 = work[c][WI(k1b)];
      float2 Xb = make_float2(z0.x - q1.x + q2.x, z0.y - q1.y + q2.y);
      ma[c] = logf(sqrtf(Xa.x*Xa.x + Xa.y*Xa.y) + 1.f);   // kh = t     -> u = t+192
      mb[c] = logf(sqrtf(Xb.x*Xb.x + Xb.y*Xb.y) + 1.f);   // kh = t+192 -> u = t
      int kw = kw0 + c;
      float wgt = (kw >= 1 && kw <= 191) ? 2.f : 1.f;
      s1 += wgt*(ma[c] + mb[c]);
      s2 += wgt*(ma[c]*ma[c] + mb[c]*mb[c]);
    }
  }
  __syncthreads();                         // done reading work
  #pragma unroll
  for (int c = 0; c < 8; ++c){
    if (c < cols){
      mgp[(t + 192)*9 + c] = ma[c];
      mgp[t*9 + c]         = mb[c];
    }
  }
  __syncthreads();
  if (cols == 8){
    float* Bhc = Bh + (size_t)bc*NS*BHW;
    #pragma unroll
    for (int rr = 0; rr < 2; ++rr){
      int u = t + rr*192;
      float* row = Bhc + (size_t)u*BHW + kw0;     // j = kw -> v = kw+192
      *(float4*)(row)     = make_float4(mgp[u*9+0], mgp[u*9+1], mgp[u*9+2], mgp[u*9+3]);
      *(float4*)(row + 4) = make_float4(mgp[u*9+4], mgp[u*9+5], mgp[u*9+6], mgp[u*9+7]);
    }
  } else {                                 // kw = 192 -> shifted col v = 0
    float* c0c = col0 + (size_t)bc*NS;
    #pragma unroll
    for (int rr = 0; rr < 2; ++rr){
      int u = t + rr*192;
      c0c[u] = mgp[u*9];
    }
  }
  float w1s = wave_sum(s1), w2s = wave_sum(s2);
  if ((t & 63) == 0){ rs[t >> 6] = w1s; rs[3 + (t >> 6)] = w2s; }
  __syncthreads();
  if (t == 0){
    atomicAdd(&stats[bc*2],     rs[0] + rs[1] + rs[2]);
    atomicAdd(&stats[bc*2 + 1], rs[3] + rs[4] + rs[5]);
  }
}

__global__ void k_finalize(const float* __restrict__ stats, const float* __restrict__ rgbsum,
                           float* __restrict__ ss, float* __restrict__ rgbmean){
  int t = threadIdx.x;
  if (t < NIMG){
    const float inv_n = 1.f / 147456.f;
    float mean = stats[t*2] * inv_n;
    float var  = fmaxf(stats[t*2 + 1] * inv_n - mean*mean, 0.f);
    float inv  = 1.f / (sqrtf(var) + 1e-8f);
    ss[t*2]     = inv;
    ss[t*2 + 1] = -mean * inv;
    rgbmean[t]  = rgbsum[t] * inv_n;
  }
}

// conv1(7x7,s2,p3)+BN+ReLU via MFMA (unchanged from round 15/17).
__global__ __launch_bounds__(256) void k_conv1mfma(const float* __restrict__ Bh,
    const float* __restrict__ col0, const float* __restrict__ ss,
    const unsigned short* __restrict__ w1p, const float* __restrict__ b1,
    const float* __restrict__ g1, const float* __restrict__ bb1,
    unsigned short* __restrict__ E, int b0){
  __shared__ unsigned short pt[3*37*40];
  int blk = blockIdx.x;
  int li = blk / 144, rem = blk - li*144;
  int rg = rem / 12, cg = rem - rg*12;
  int r0 = rg*16, c0 = cg*16;
  int b = b0 + li;
  int t = threadIdx.x;
  float sc[3], sh[3];
  #pragma unroll
  for (int ic = 0; ic < 3; ++ic){ sc[ic] = ss[(b*3 + ic)*2]; sh[ic] = ss[(b*3 + ic)*2 + 1]; }
  const int h0 = 2*r0 - 3, w0 = 2*c0 - 3;
  for (int lin = t; lin < 3*37*40; lin += 256){
    int ic = lin / 1480; int r = lin - ic*1480;
    int hr = r / 40, wc = r - hr*40;
    int hg = h0 + hr, wg = w0 + wc;
    bool v = (wc < 38) && ((unsigned)hg < (unsigned)NS) && ((unsigned)wg < (unsigned)NS);
    float raw = 0.f;
    if (v){
      const float* Bc = Bh + (size_t)(b*3 + ic)*NS*BHW;
      if (wg >= 192)      raw = Bc[(size_t)hg*BHW + (wg - 192)];
      else if (wg >= 1)   raw = Bc[(size_t)mod384(NS - hg)*BHW + (192 - wg)];
      else                raw = col0[(size_t)(b*3 + ic)*NS + hg];
    }
    pt[lin] = v ? f2bf(fmaf(raw, sc[ic], sh[ic])) : (unsigned short)0;
  }
  __syncthreads();

  int wave = t >> 6, lane = t & 63;
  int lm = lane & 15, lg = lane >> 4;
  U16 bf[6];
  #pragma unroll
  for (int ks = 0; ks < 6; ++ks)
    bf[ks].q = *(const uint4*)(w1p + (wave*16 + lm)*192 + ks*32 + lg*8);
  int cbase[6];
  #pragma unroll
  for (int ks = 0; ks < 6; ++ks){
    int rk = ks*4 + lg;
    if (rk > 20) rk = 20;
    int ic = rk / 7, kh = rk - 7*ic;
    cbase[ks] = ic*1480 + kh*40 + 2*lm;
  }
  const float bneps = rsqrtf(1.f + 1e-5f);
  float4 b4  = *(const float4*)(b1  + wave*16 + lg*4);
  float4 g4  = *(const float4*)(g1  + wave*16 + lg*4);
  float4 bb4 = *(const float4*)(bb1 + wave*16 + lg*4);
  float4 gs4 = make_float4(g4.x*bneps, g4.y*bneps, g4.z*bneps, g4.w*bneps);
  unsigned short* Eb = E + (((size_t)li*C1DIM + r0)*C1DIM + c0 + lm)*64 + wave*16 + lg*4;

  #pragma unroll 1
  for (int rt = 0; rt < 16; ++rt){
    f32x4_t acc = {b4.x, b4.y, b4.z, b4.w};
    #pragma unroll
    for (int ks = 0; ks < 6; ++ks){
      U16 a;
      const unsigned* pp = (const unsigned*)&pt[cbase[ks] + 80*rt];
      a.u[0] = pp[0]; a.u[1] = pp[1]; a.u[2] = pp[2]; a.u[3] = pp[3];
      acc = __builtin_amdgcn_mfma_f32_16x16x32_bf16(bf[ks].v, a.v, acc, 0, 0, 0);
    }
    ushort4 o;
    o.x = f2bf(fmaxf(fmaf(acc[0], gs4.x, bb4.x), 0.f));
    o.y = f2bf(fmaxf(fmaf(acc[1], gs4.y, bb4.y), 0.f));
    o.z = f2bf(fmaxf(fmaf(acc[2], gs4.z, bb4.z), 0.f));
    o.w = f2bf(fmaxf(fmaf(acc[3], gs4.w, bb4.w), 0.f));
    *(ushort4*)(Eb + (size_t)rt*C1DIM*64) = o;
  }
}

// maxpool 3x3 s2 p1 over E -> P bf16[cvB][96][96][64] (unchanged from r15).
__global__ __launch_bounds__(256) void k_pool(const unsigned short* __restrict__ E,
    unsigned short* __restrict__ P){
  int lin = blockIdx.x*256 + (int)threadIdx.x;   // ((li*96+ph)*96+pw)*8+g
  int g = lin & 7; int rm = lin >> 3;
  int pw = rm % PDIM; int rm2 = rm / PDIM;
  int ph = rm2 % PDIM; int li = rm2 / PDIM;
  const unsigned short* Eb = E + (size_t)li*C1DIM*C1DIM*64 + g*8;
  uint4 mx = make_uint4(0u,0u,0u,0u);
  #pragma unroll
  for (int dh = 0; dh < 3; ++dh){
    int eh = 2*ph - 1 + dh;
    if ((unsigned)eh >= (unsigned)C1DIM) continue;
    #pragma unroll
    for (int dw = 0; dw < 3; ++dw){
      int ew = 2*pw - 1 + dw;
      if ((unsigned)ew >= (unsigned)C1DIM) continue;
      mx = pmax8(mx, *(const uint4*)(Eb + ((size_t)eh*C1DIM + ew)*64));
    }
  }
  *(uint4*)(P + ((size_t)rm)*64 + g*8) = mx;
}

// conv2(3x3,p1)+BN+ReLU + global-avg-pool via MFMA — ROUND-15 GEOMETRY
// (512 thr / 8 waves x 16 oc, VGPR~120, measured best: 82-83 us).
// r16 (4-wave oc-split) and r18 (32-oc waves) BOTH regressed: r16 doubled
// the weight/halo streams; r18's VGPR 152 crushed occupancy (9.3%).
// This config is the {streams x occupancy} local optimum — do not restructure.
// Added: s_setprio(1) around the MFMA loop (T5; applies here because the 2
// resident blocks/CU are at different phases: one staging, one in MFMA).
__global__ __launch_bounds__(512) void k_conv2mfma(const unsigned short* __restrict__ P,
    const unsigned short* __restrict__ w2ph, const unsigned short* __restrict__ w2pl,
    const float* __restrict__ b2, const float* __restrict__ g2,
    const float* __restrict__ bb2, float* __restrict__ freq_acc, int b0){
  __shared__ unsigned short sD[10*1152];   // [hp(10)][g(8)][wp(18)][8ic]
  int blk = blockIdx.x;
  int li = blk / 72, tile = blk - li*72;
  int rb = tile / 6, cb = tile - rb*6;
  int r0 = rb*8, c0 = cb*16;
  int b = b0 + li;
  int t = threadIdx.x;
  const unsigned short* Pb = P + (size_t)li*PHW*64;
  for (int lin = t; lin < 1440; lin += 512){
    int g = lin & 7; int rm = lin >> 3;
    int wp = rm % 18, hp = rm / 18;
    int ph = r0 + hp - 1, pw = c0 + wp - 1;
    uint4 v = make_uint4(0u,0u,0u,0u);
    if ((unsigned)ph < (unsigned)PDIM && (unsigned)pw < (unsigned)PDIM)
      v = *(const uint4*)(Pb + ((size_t)ph*PDIM + pw)*64 + g*8);
    *(uint4*)&sD[hp*1152 + g*144 + wp*8] = v;
  }
  __syncthreads();

  int wave = t >> 6, lane = t & 63;
  int lm = lane & 15, lg = lane >> 4;
  int octile = wave*16;
  const float bneps = rsqrtf(1.f + 1e-5f);
  float4 b4  = *(const float4*)(b2  + octile + lg*4);
  float4 g4  = *(const float4*)(g2  + octile + lg*4);
  float4 bb4 = *(const float4*)(bb2 + octile + lg*4);
  f32x4_t acc[8];
  #pragma unroll
  for (int nt = 0; nt < 8; ++nt){
    acc[nt][0] = b4.x; acc[nt][1] = b4.y; acc[nt][2] = b4.z; acc[nt][3] = b4.w;
  }
  const unsigned short* whp = w2ph + (size_t)(octile + lm)*576;
  const unsigned short* wlp = w2pl + (size_t)(octile + lm)*576;
  __builtin_amdgcn_s_setprio(1);
  #pragma unroll
  for (int ks = 0; ks < 18; ++ks){
    const int tap = ks >> 1, h32 = ks & 1;
    const int dh = tap / 3, dw = tap - 3*(tap/3);
    U16 wh, wl;
    wh.q = *(const uint4*)(whp + ks*32 + lg*8);
    wl.q = *(const uint4*)(wlp + ks*32 + lg*8);
    int base = (h32*4 + lg)*144 + (lm + dw)*8;
    #pragma unroll
    for (int nt = 0; nt < 8; ++nt){
      U16 a;
      a.q = *(const uint4*)&sD[(nt + dh)*1152 + base];
      acc[nt] = __builtin_amdgcn_mfma_f32_16x16x32_bf16(wh.v, a.v, acc[nt], 0, 0, 0);
      acc[nt] = __builtin_amdgcn_mfma_f32_16x16x32_bf16(wl.v, a.v, acc[nt], 0, 0, 0);
    }
  }
  __builtin_amdgcn_s_setprio(0);
  float s0 = 0.f, s1 = 0.f, s2 = 0.f, s3 = 0.f;
  float gx = g4.x*bneps, gy = g4.y*bneps, gz = g4.z*bneps, gw = g4.w*bneps;
  #pragma unroll
  for (int nt = 0; nt < 8; ++nt){
    s0 += fmaxf(fmaf(acc[nt][0], gx, bb4.x), 0.f);
    s1 += fmaxf(fmaf(acc[nt][1], gy, bb4.y), 0.f);
    s2 += fmaxf(fmaf(acc[nt][2], gz, bb4.z), 0.f);
    s3 += fmaxf(fmaf(acc[nt][3], gw, bb4.w), 0.f);
  }
  #pragma unroll
  for (int off = 1; off < 16; off <<= 1){
    s0 += __shfl_xor(s0, off);
    s1 += __shfl_xor(s1, off);
    s2 += __shfl_xor(s2, off);
    s3 += __shfl_xor(s3, off);
  }
  if (lm == 0){
    float* fa = freq_acc + (size_t)b*C2OUT + octile + lg*4;
    atomicAdd(fa + 0, s0); atomicAdd(fa + 1, s1);
    atomicAdd(fa + 2, s2); atomicAdd(fa + 3, s3);
  }
}

// RGB head + concat + 3-layer MLP, one block per batch sample.
__global__ __launch_bounds__(256) void k_mlp(const float* __restrict__ rgbmean,
    const float* __restrict__ freq_acc, const float* __restrict__ w_rgb,
    const float* __restrict__ b_rgb, const float* __restrict__ fc1w,
    const float* __restrict__ fc1b, const float* __restrict__ fc2w,
    const float* __restrict__ fc2b, const float* __restrict__ fc3w,
    const float* __restrict__ fc3b, float* __restrict__ out){
  __shared__ float z[130], z1[256], z2[128];
  int b = blockIdx.x, t = threadIdx.x;
  if (t < 2){
    float s = b_rgb[t];
    #pragma unroll
    for (int c = 0; c < 3; ++c) s += rgbmean[b*3 + c] * w_rgb[c*2 + t];
    z[t] = s;
  }
  if (t < 128) z[2 + t] = freq_acc[b*C2OUT + t] * (1.f/9216.f);
  __syncthreads();
  { float s = fc1b[t];
    for (int k = 0; k < 130; ++k) s = fmaf(z[k], fc1w[k*256 + t], s);
    z1[t] = fmaxf(s, 0.f); }
  __syncthreads();
  if (t < 128){
    float s = fc2b[t];
    for (int k = 0; k < 256; ++k) s = fmaf(z1[k], fc2w[k*128 + t], s);
    z2[t] = fmaxf(s, 0.f); }
  __syncthreads();
  if (t < 2){
    float s = fc3b[t];
    for (int k = 0; k < 128; ++k) s = fmaf(z2[k], fc3w[k*2 + t], s);
    out[b*2 + t] = s; }
}

extern "C" void kernel_launch(void* const* d_in, const int* in_sizes, int n_in,
                              void* d_out, int out_size, void* d_ws, size_t ws_size,
                              hipStream_t stream){
  const float* x     = (const float*)d_in[0];
  const float* w_rgb = (const float*)d_in[1];
  const float* b_rgb = (const float*)d_in[2];
  const float* w1    = (const float*)d_in[3];
  const float* b1    = (const float*)d_in[4];
  const float* g1    = (const float*)d_in[5];
  const float* bb1   = (const float*)d_in[6];
  const float* w2    = (const float*)d_in[7];
  const float* b2    = (const float*)d_in[8];
  const float* g2    = (const float*)d_in[9];
  const float* bb2   = (const float*)d_in[10];
  const float* fc1w  = (const float*)d_in[11];
  const float* fc1b  = (const float*)d_in[12];
  const float* fc2w  = (const float*)d_in[13];
  const float* fc2b  = (const float*)d_in[14];
  const float* fc3w  = (const float*)d_in[15];
  const float* fc3b  = (const float*)d_in[16];

  const bool full = (ws_size >= NEED_F);
  const int dftloop = full ? 1 : 4;
  const int dftCH   = full ? 96 : 24;
  const int cvloop  = full ? 2 : 16;
  const int cvB     = full ? 16 : 2;

  char* ws = (char*)d_ws;
  float2* T  = (float2*)(ws + OFF_T);
  unsigned short* w1p  = (unsigned short*)(ws + OFF_TW1);
  unsigned short* w2ph = (unsigned short*)(ws + OFF_TW2H);
  unsigned short* w2pl = (unsigned short*)(ws + OFF_TW2L);
  float*  Bh   = (float*)(ws + OFF_B);
  float*  col0 = (float*)(ws + OFF_C0);
  unsigned short* P = (unsigned short*)(ws + OFF_P);
  float2* A    = (float2*)(ws + OFF_S);
  unsigned short* E = (unsigned short*)(ws + OFF_S);
  float*  sm = (float*)(ws + (full ? OFF_SM_F : OFF_SM_C));
  float* rgbsum = sm;            // 96
  float* stats  = sm + 96;       // 192
  float* freqa  = sm + 288;      // 4096
  float* rgbm   = sm + 4384;     // 96
  float* ssb    = sm + 4480;     // 192

  hipMemsetAsync(sm, 0, 4672*sizeof(float), stream);
  k_prep<<<288, 256, 0, stream>>>(w1, w2, T, w1p, w2ph, w2pl);
  for (int c = 0; c < dftloop; ++c){
    k_dft_rows<<<dftCH*48, 192, 0, stream>>>(x, T, A, rgbsum, c*dftCH);
    k_dft_cols<<<dftCH*25, 192, 0, stream>>>(A, T, Bh, col0, stats, c*dftCH);
  }
  k_finalize<<<1, 128, 0, stream>>>(stats, rgbsum, ssb, rgbm);
  for (int c = 0; c < cvloop; ++c){
    k_conv1mfma<<<cvB*144, 256, 0, stream>>>(Bh, col0, ssb, w1p, b1, g1, bb1, E, c*cvB);
    k_pool<<<cvB*288, 256, 0, stream>>>(E, P);
    k_conv2mfma<<<cvB*72, 512, 0, stream>>>(P, w2ph, w2pl, b2, g2, bb2, freqa, c*cvB);
  }
  k_mlp<<<NB, 256, 0, stream>>>(rgbm, freqa, w_rgb, b_rgb, fc1w, fc1b,
                                fc2w, fc2b, fc3w, fc3b, (float*)d_out);
}

// Round 20
// 344.425 us; speedup vs baseline: 1.1564x; 1.1265x over previous
//
#include <hip/hip_runtime.h>
#include <math.h>

// Problem dims
#define NB    32
#define NC    3
#define NIMG  (NB*NC)      // 96 image-channels
#define NS    384
#define HWSZ  (NS*NS)      // 147456
#define C1OUT 64
#define C1DIM 192
#define PDIM  96
#define PHW   (PDIM*PDIM)  // 9216
#define C2OUT 128
#define KWH   200          // A row stride (padded 193->200: 64B-aligned rows)
#define BHW   192          // stored half-spectrum width in Bh (v = 192..383)
#define PI_F  3.14159265358979323846f

// ---- workspace layout (bytes) ----
// T region @0: twiddle row f2[768], w1p @8192, w2ph @32768 (w2 lo-split REMOVED r20)
// B region @OFF_B: Bh f32[96][384][192] = 28,311,552 + col0 f32[96][384]
// P region @OFF_P: P bf16[16][96][96][64] = 18,874,368 (pooled conv1, chunk-local)
// S region @OFF_S (75,497,472, time-shared):
//   dft phase : A float2[96][384][200] = 58,982,400 (full) / [24] (chunked)
//   conv phase: E bf16[16][192][192][64] = 75,497,472 (full) / [2] (chunked)
// smalls @OFF_SM
static const size_t OFF_T    = 0;
static const size_t OFF_TW1  = 8192;
static const size_t OFF_TW2H = 32768;
static const size_t OFF_B    = 1179648;
static const size_t OFF_C0   = 1179648 + 28311552;   // col0
static const size_t OFF_P    = 29638656;             // after col0 (147,456)
static const size_t OFF_S    = 57802752;
static const size_t OFF_SM_F = 133300224;
static const size_t OFF_SM_C = 76677120;
static const size_t NEED_F   = 133318912;

// padded LDS index for FFT work arrays: breaks 2^k-stride bank conflicts
#define WI(i) ((i) + ((i) >> 4))

typedef __attribute__((ext_vector_type(8))) short bf16x8_t;
typedef __attribute__((ext_vector_type(4))) float f32x4_t;
union U16 { unsigned u[4]; uint4 q; bf16x8_t v; };

__device__ __forceinline__ float wave_sum(float v){
  #pragma unroll
  for (int off = 32; off; off >>= 1) v += __shfl_down(v, off);
  return v;
}
__device__ __forceinline__ unsigned short f2bf(float f){
  unsigned u = __float_as_uint(f);
  u += 0x7FFFu + ((u >> 16) & 1u);
  return (unsigned short)(u >> 16);
}
__device__ __forceinline__ float bf2f(unsigned short h){
  return __uint_as_float(((unsigned)h) << 16);
}
__device__ __forceinline__ unsigned pmax16(unsigned a, unsigned b){
  unsigned al = a & 0xffffu, ah = a >> 16, bl = b & 0xffffu, bh = b >> 16;
  unsigned ml = al > bl ? al : bl, mh = ah > bh ? ah : bh;
  return (mh << 16) | ml;
}
__device__ __forceinline__ uint4 pmax8(uint4 a, uint4 b){
  uint4 r;
  r.x = pmax16(a.x, b.x); r.y = pmax16(a.y, b.y);
  r.z = pmax16(a.z, b.z); r.w = pmax16(a.w, b.w);
  return r;
}
// proper mod-384 for v in [0, 768): NOT "& 383" (384 not a power of two).
__device__ __forceinline__ int mod384(int v){ return v >= NS ? v - NS : v; }
__device__ __forceinline__ float2 cmul(float2 a, float2 b){
  return make_float2(a.x*b.x - a.y*b.y, a.x*b.y + a.y*b.x);
}

// Merged prep: twiddle row W384^m + conv1 bf16 weight pack + conv2 bf16 pack.
__global__ void k_prep(const float* __restrict__ w1, const float* __restrict__ w2,
    float2* __restrict__ T, unsigned short* __restrict__ w1p,
    unsigned short* __restrict__ w2ph){
  int idx = blockIdx.x*256 + (int)threadIdx.x;
  if (idx < NS){
    float ang = -2.0f*PI_F*(float)idx/(float)NS;
    T[NS + idx] = make_float2(cosf(ang), sinf(ang));
  }
  if (idx < 64*192){
    int oc = idx / 192, k = idx - oc*192;
    int rk = k >> 3, kw = k & 7;
    float val = 0.f;
    if (rk < 21 && kw < 7){
      int ic = rk / 7, kh = rk - 7*ic;
      val = w1[oc*147 + ic*49 + kh*7 + kw];
    }
    w1p[idx] = f2bf(val);
  }
  if (idx < 128*576){
    int oc = idx / 576, k = idx - oc*576;
    int tap = k >> 6, ic = k & 63;
    w2ph[idx] = f2bf(w2[(size_t)oc*576 + ic*9 + tap]);
  }
}

// Row FFT (along W, real input): 8 rows/block as 4 packed complex FFTs.
__global__ __launch_bounds__(192) void k_dft_rows(const float* __restrict__ x,
    const float2* __restrict__ T, float2* __restrict__ A,
    float* __restrict__ rgbsum, int bc0){
  __shared__ float2 work[4][408];          // WI(383)=406 max
  __shared__ float rs[3];
  const float2* Trow = T + NS;             // W384^m
  int blk = blockIdx.x;
  int bcl = blk / 48, rg = blk % 48;
  int bc = bc0 + bcl;
  int t = threadIdx.x;
  const float* xp = x + (size_t)bc*HWSZ + (size_t)rg*8*NS;
  int nA = t,        rA = nA % 3, iA = (rA*128) + (__brev((unsigned)(nA/3)) >> 25);
  int nB = t + 192,  rB = nB % 3, iB = (rB*128) + (__brev((unsigned)(nB/3)) >> 25);
  float lsum = 0.f;
  #pragma unroll
  for (int c = 0; c < 4; ++c){
    float a0 = xp[(2*c)*NS + nA],   b0 = xp[(2*c+1)*NS + nA];
    float a1 = xp[(2*c)*NS + nB],   b1 = xp[(2*c+1)*NS + nB];
    work[c][WI(iA)] = make_float2(a0, b0);
    work[c][WI(iB)] = make_float2(a1, b1);
    lsum += a0 + b0 + a1 + b1;
  }
  float ws = wave_sum(lsum);
  if ((t & 63) == 0) rs[t >> 6] = ws;
  __syncthreads();
  if (t == 0) atomicAdd(&rgbsum[bc], rs[0] + rs[1] + rs[2]);

  int sub = t >> 6, j = t & 63;
  #pragma unroll
  for (int st = 0; st < 7; ++st){
    int half = 1 << st;
    int pos = j & (half - 1);
    int ia = sub*128 + (((j >> st) << (st + 1)) | pos);
    int ib = ia + half;
    float2 tw = Trow[(192 >> st) * pos];
    #pragma unroll
    for (int c = 0; c < 4; ++c){
      float2 a = work[c][WI(ia)], b = cmul(work[c][WI(ib)], tw);
      work[c][WI(ia)] = make_float2(a.x + b.x, a.y + b.y);
      work[c][WI(ib)] = make_float2(a.x - b.x, a.y - b.y);
    }
    __syncthreads();
  }
  int k1a = t & 127, k1b = (t + 192) & 127;
  float2 w1 = Trow[t], w2 = Trow[(2*t) % 384];
  float2 Xa[4], Xb[4];
  #pragma unroll
  for (int c = 0; c < 4; ++c){
    float2 p1 = cmul(w1, work[c][WI(128 + k1a)]);
    float2 p2 = cmul(w2, work[c][WI(256 + k1a)]);
    float2 y0 = work[c][WI(k1a)];
    Xa[c] = make_float2(y0.x + p1.x + p2.x, y0.y + p1.y + p2.y);
    float2 q1 = cmul(w1, work[c][WI(128 + k1b)]);
    float2 q2 = cmul(w2, work[c][WI(256 + k1b)]);
    float2 z0 = work[c][WI(k1b)];
    Xb[c] = make_float2(z0.x - q1.x + q2.x, z0.y - q1.y + q2.y);
  }
  __syncthreads();
  #pragma unroll
  for (int c = 0; c < 4; ++c){ work[c][WI(t)] = Xa[c]; work[c][WI(t + 192)] = Xb[c]; }
  __syncthreads();
  int tm = (t == 0) ? 0 : (384 - t);
  #pragma unroll
  for (int c = 0; c < 4; ++c){
    float2 Zk = Xa[c];
    float2 Zm = work[c][WI(tm)];
    size_t b0r = ((size_t)bcl*NS + rg*8 + 2*c)*KWH;
    size_t b1r = b0r + KWH;
    A[b0r + t] = make_float2(0.5f*(Zk.x + Zm.x), 0.5f*(Zk.y - Zm.y));
    A[b1r + t] = make_float2(0.5f*(Zk.y + Zm.y), 0.5f*(Zm.x - Zk.x));
    if (t == 0){
      float2 Zn = Xb[c];
      A[b0r + 192] = make_float2(Zn.x, 0.f);
      A[b1r + 192] = make_float2(Zn.y, 0.f);
    }
  }
}

// Column FFT for kw in [0,192], 8 columns/block. Half-spectrum output (r13).
__global__ __launch_bounds__(192) void k_dft_cols(const float2* __restrict__ A,
    const float2* __restrict__ T, float* __restrict__ Bh, float* __restrict__ col0,
    float* __restrict__ stats, int bc0){
  __shared__ float2 work[8][408];
  __shared__ float rs[6];
  float* mgp = (float*)work;               // overlay after combine: mg[u][c] = mgp[u*9+c]
  const float2* Trow = T + NS;
  int blk = blockIdx.x;
  int bcl = blk / 25, cg = blk % 25;
  int bc = bc0 + bcl;
  int kw0 = cg*8;
  int cols = (cg == 24) ? 1 : 8;
  int t = threadIdx.x;
  const float2* Al = A + (size_t)bcl*NS*KWH;
  if (cols == 8){
    #pragma unroll
    for (int i = 0; i < 16; ++i){
      int lin = i*192 + t;
      int h = lin >> 3, c = lin & 7;
      int r = h % 3;
      work[c][WI(r*128 + (__brev((unsigned)(h/3)) >> 25))] = Al[(size_t)h*KWH + kw0 + c];
    }
  } else {
    for (int h = t; h < NS; h += 192){
      int r = h % 3;
      work[0][WI(r*128 + (__brev((unsigned)(h/3)) >> 25))] = Al[(size_t)h*KWH + kw0];
    }
  }
  __syncthreads();
  int sub = t >> 6, j = t & 63;
  #pragma unroll
  for (int st = 0; st < 7; ++st){
    int half = 1 << st;
    int pos = j & (half - 1);
    int ia = sub*128 + (((j >> st) << (st + 1)) | pos);
    int ib = ia + half;
    float2 tw = Trow[(192 >> st) * pos];
    #pragma unroll
    for (int c = 0; c < 8; ++c){
      if (c < cols){
        float2 a = work[c][WI(ia)], b = cmul(work[c][WI(ib)], tw);
        work[c][WI(ia)] = make_float2(a.x + b.x, a.y + b.y);
        work[c][WI(ib)] = make_float2(a.x - b.x, a.y - b.y);
      }
    }
    __syncthreads();
  }
  int k1a = t & 127, k1b = (t + 192) & 127;
  float2 w1 = Trow[t], w2 = Trow[(2*t) % 384];
  float s1 = 0.f, s2 = 0.f;
  float ma[8], mb[8];
  #pragma unroll
  for (int c = 0; c < 8; ++c){
    ma[c] = 0.f; mb[c] = 0.f;
    if (c < cols){
      float2 p1 = cmul(w1, work[c][WI(128 + k1a)]);
      float2 p2 = cmul(w2, work[c][WI(256 + k1a)]);
      float2 y0 = work[c][WI(k1a)];
      float2 Xa = make_float2(y0.x + p1.x + p2.x, y0.y + p1.y + p2.y);
      float2 q1 = cmul(w1, work[c][WI(128 + k1b)]);
      float2 q2 = cmul(w2, work[c][WI(256 + k1b)]);
      float2 z0 = work[c][WI(k1b)];
      float2 Xb = make_float2(z0.x - q1.x + q2.x, z0.y - q1.y + q2.y);
      ma[c] = logf(sqrtf(Xa.x*Xa.x + Xa.y*Xa.y) + 1.f);   // kh = t     -> u = t+192
      mb[c] = logf(sqrtf(Xb.x*Xb.x + Xb.y*Xb.y) + 1.f);   // kh = t+192 -> u = t
      int kw = kw0 + c;
      float wgt = (kw >= 1 && kw <= 191) ? 2.f : 1.f;
      s1 += wgt*(ma[c] + mb[c]);
      s2 += wgt*(ma[c]*ma[c] + mb[c]*mb[c]);
    }
  }
  __syncthreads();                         // done reading work
  #pragma unroll
  for (int c = 0; c < 8; ++c){
    if (c < cols){
      mgp[(t + 192)*9 + c] = ma[c];
      mgp[t*9 + c]         = mb[c];
    }
  }
  __syncthreads();
  if (cols == 8){
    float* Bhc = Bh + (size_t)bc*NS*BHW;
    #pragma unroll
    for (int rr = 0; rr < 2; ++rr){
      int u = t + rr*192;
      float* row = Bhc + (size_t)u*BHW + kw0;     // j = kw -> v = kw+192
      *(float4*)(row)     = make_float4(mgp[u*9+0], mgp[u*9+1], mgp[u*9+2], mgp[u*9+3]);
      *(float4*)(row + 4) = make_float4(mgp[u*9+4], mgp[u*9+5], mgp[u*9+6], mgp[u*9+7]);
    }
  } else {                                 // kw = 192 -> shifted col v = 0
    float* c0c = col0 + (size_t)bc*NS;
    #pragma unroll
    for (int rr = 0; rr < 2; ++rr){
      int u = t + rr*192;
      c0c[u] = mgp[u*9];
    }
  }
  float w1s = wave_sum(s1), w2s = wave_sum(s2);
  if ((t & 63) == 0){ rs[t >> 6] = w1s; rs[3 + (t >> 6)] = w2s; }
  __syncthreads();
  if (t == 0){
    atomicAdd(&stats[bc*2],     rs[0] + rs[1] + rs[2]);
    atomicAdd(&stats[bc*2 + 1], rs[3] + rs[4] + rs[5]);
  }
}

__global__ void k_finalize(const float* __restrict__ stats, const float* __restrict__ rgbsum,
                           float* __restrict__ ss, float* __restrict__ rgbmean){
  int t = threadIdx.x;
  if (t < NIMG){
    const float inv_n = 1.f / 147456.f;
    float mean = stats[t*2] * inv_n;
    float var  = fmaxf(stats[t*2 + 1] * inv_n - mean*mean, 0.f);
    float inv  = 1.f / (sqrtf(var) + 1e-8f);
    ss[t*2]     = inv;
    ss[t*2 + 1] = -mean * inv;
    rgbmean[t]  = rgbsum[t] * inv_n;
  }
}

// conv1(7x7,s2,p3)+BN+ReLU via MFMA (unchanged from round 15/17).
__global__ __launch_bounds__(256) void k_conv1mfma(const float* __restrict__ Bh,
    const float* __restrict__ col0, const float* __restrict__ ss,
    const unsigned short* __restrict__ w1p, const float* __restrict__ b1,
    const float* __restrict__ g1, const float* __restrict__ bb1,
    unsigned short* __restrict__ E, int b0){
  __shared__ unsigned short pt[3*37*40];
  int blk = blockIdx.x;
  int li = blk / 144, rem = blk - li*144;
  int rg = rem / 12, cg = rem - rg*12;
  int r0 = rg*16, c0 = cg*16;
  int b = b0 + li;
  int t = threadIdx.x;
  float sc[3], sh[3];
  #pragma unroll
  for (int ic = 0; ic < 3; ++ic){ sc[ic] = ss[(b*3 + ic)*2]; sh[ic] = ss[(b*3 + ic)*2 + 1]; }
  const int h0 = 2*r0 - 3, w0 = 2*c0 - 3;
  for (int lin = t; lin < 3*37*40; lin += 256){
    int ic = lin / 1480; int r = lin - ic*1480;
    int hr = r / 40, wc = r - hr*40;
    int hg = h0 + hr, wg = w0 + wc;
    bool v = (wc < 38) && ((unsigned)hg < (unsigned)NS) && ((unsigned)wg < (unsigned)NS);
    float raw = 0.f;
    if (v){
      const float* Bc = Bh + (size_t)(b*3 + ic)*NS*BHW;
      if (wg >= 192)      raw = Bc[(size_t)hg*BHW + (wg - 192)];
      else if (wg >= 1)   raw = Bc[(size_t)mod384(NS - hg)*BHW + (192 - wg)];
      else                raw = col0[(size_t)(b*3 + ic)*NS + hg];
    }
    pt[lin] = v ? f2bf(fmaf(raw, sc[ic], sh[ic])) : (unsigned short)0;
  }
  __syncthreads();

  int wave = t >> 6, lane = t & 63;
  int lm = lane & 15, lg = lane >> 4;
  U16 bf[6];
  #pragma unroll
  for (int ks = 0; ks < 6; ++ks)
    bf[ks].q = *(const uint4*)(w1p + (wave*16 + lm)*192 + ks*32 + lg*8);
  int cbase[6];
  #pragma unroll
  for (int ks = 0; ks < 6; ++ks){
    int rk = ks*4 + lg;
    if (rk > 20) rk = 20;
    int ic = rk / 7, kh = rk - 7*ic;
    cbase[ks] = ic*1480 + kh*40 + 2*lm;
  }
  const float bneps = rsqrtf(1.f + 1e-5f);
  float4 b4  = *(const float4*)(b1  + wave*16 + lg*4);
  float4 g4  = *(const float4*)(g1  + wave*16 + lg*4);
  float4 bb4 = *(const float4*)(bb1 + wave*16 + lg*4);
  float4 gs4 = make_float4(g4.x*bneps, g4.y*bneps, g4.z*bneps, g4.w*bneps);
  unsigned short* Eb = E + (((size_t)li*C1DIM + r0)*C1DIM + c0 + lm)*64 + wave*16 + lg*4;

  #pragma unroll 1
  for (int rt = 0; rt < 16; ++rt){
    f32x4_t acc = {b4.x, b4.y, b4.z, b4.w};
    #pragma unroll
    for (int ks = 0; ks < 6; ++ks){
      U16 a;
      const unsigned* pp = (const unsigned*)&pt[cbase[ks] + 80*rt];
      a.u[0] = pp[0]; a.u[1] = pp[1]; a.u[2] = pp[2]; a.u[3] = pp[3];
      acc = __builtin_amdgcn_mfma_f32_16x16x32_bf16(bf[ks].v, a.v, acc, 0, 0, 0);
    }
    ushort4 o;
    o.x = f2bf(fmaxf(fmaf(acc[0], gs4.x, bb4.x), 0.f));
    o.y = f2bf(fmaxf(fmaf(acc[1], gs4.y, bb4.y), 0.f));
    o.z = f2bf(fmaxf(fmaf(acc[2], gs4.z, bb4.z), 0.f));
    o.w = f2bf(fmaxf(fmaf(acc[3], gs4.w, bb4.w), 0.f));
    *(ushort4*)(Eb + (size_t)rt*C1DIM*64) = o;
  }
}

// maxpool 3x3 s2 p1 over E -> P bf16[cvB][96][96][64] (unchanged from r15).
__global__ __launch_bounds__(256) void k_pool(const unsigned short* __restrict__ E,
    unsigned short* __restrict__ P){
  int lin = blockIdx.x*256 + (int)threadIdx.x;   // ((li*96+ph)*96+pw)*8+g
  int g = lin & 7; int rm = lin >> 3;
  int pw = rm % PDIM; int rm2 = rm / PDIM;
  int ph = rm2 % PDIM; int li = rm2 / PDIM;
  const unsigned short* Eb = E + (size_t)li*C1DIM*C1DIM*64 + g*8;
  uint4 mx = make_uint4(0u,0u,0u,0u);
  #pragma unroll
  for (int dh = 0; dh < 3; ++dh){
    int eh = 2*ph - 1 + dh;
    if ((unsigned)eh >= (unsigned)C1DIM) continue;
    #pragma unroll
    for (int dw = 0; dw < 3; ++dw){
      int ew = 2*pw - 1 + dw;
      if ((unsigned)ew >= (unsigned)C1DIM) continue;
      mx = pmax8(mx, *(const uint4*)(Eb + ((size_t)eh*C1DIM + ew)*64));
    }
  }
  *(uint4*)(P + ((size_t)rm)*64 + g*8) = mx;
}

// conv2(3x3,p1)+BN+ReLU + global-avg-pool via MFMA — round-15 geometry
// (512 thr / 8 waves x 16 oc; measured local optimum). Round-20: SINGLE
// bf16 MFMA per (ks,nt) — the hi/lo exact-weight split removed. Error
// budget: weight rounding adds ~1.2e-3 per pooled feature -> ~3e-4 at the
// final output; measured baseline absmax 9.77e-4 vs threshold 2.87e-3.
// Halves MFMA work, weight stream, and acc dependency depth.
__global__ __launch_bounds__(512) void k_conv2mfma(const unsigned short* __restrict__ P,
    const unsigned short* __restrict__ w2ph,
    const float* __restrict__ b2, const float* __restrict__ g2,
    const float* __restrict__ bb2, float* __restrict__ freq_acc, int b0){
  __shared__ unsigned short sD[10*1152];   // [hp(10)][g(8)][wp(18)][8ic]
  int blk = blockIdx.x;
  int li = blk / 72, tile = blk - li*72;
  int rb = tile / 6, cb = tile - rb*6;
  int r0 = rb*8, c0 = cb*16;
  int b = b0 + li;
  int t = threadIdx.x;
  const unsigned short* Pb = P + (size_t)li*PHW*64;
  for (int lin = t; lin < 1440; lin += 512){
    int g = lin & 7; int rm = lin >> 3;
    int wp = rm % 18, hp = rm / 18;
    int ph = r0 + hp - 1, pw = c0 + wp - 1;
    uint4 v = make_uint4(0u,0u,0u,0u);
    if ((unsigned)ph < (unsigned)PDIM && (unsigned)pw < (unsigned)PDIM)
      v = *(const uint4*)(Pb + ((size_t)ph*PDIM + pw)*64 + g*8);
    *(uint4*)&sD[hp*1152 + g*144 + wp*8] = v;
  }
  __syncthreads();

  int wave = t >> 6, lane = t & 63;
  int lm = lane & 15, lg = lane >> 4;
  int octile = wave*16;
  const float bneps = rsqrtf(1.f + 1e-5f);
  float4 b4  = *(const float4*)(b2  + octile + lg*4);
  float4 g4  = *(const float4*)(g2  + octile + lg*4);
  float4 bb4 = *(const float4*)(bb2 + octile + lg*4);
  f32x4_t acc[8];
  #pragma unroll
  for (int nt = 0; nt < 8; ++nt){
    acc[nt][0] = b4.x; acc[nt][1] = b4.y; acc[nt][2] = b4.z; acc[nt][3] = b4.w;
  }
  const unsigned short* whp = w2ph + (size_t)(octile + lm)*576;
  __builtin_amdgcn_s_setprio(1);
  #pragma unroll
  for (int ks = 0; ks < 18; ++ks){
    const int tap = ks >> 1, h32 = ks & 1;
    const int dh = tap / 3, dw = tap - 3*(tap/3);
    U16 wh;
    wh.q = *(const uint4*)(whp + ks*32 + lg*8);
    int base = (h32*4 + lg)*144 + (lm + dw)*8;
    #pragma unroll
    for (int nt = 0; nt < 8; ++nt){
      U16 a;
      a.q = *(const uint4*)&sD[(nt + dh)*1152 + base];
      acc[nt] = __builtin_amdgcn_mfma_f32_16x16x32_bf16(wh.v, a.v, acc[nt], 0, 0, 0);
    }
  }
  __builtin_amdgcn_s_setprio(0);
  float s0 = 0.f, s1 = 0.f, s2 = 0.f, s3 = 0.f;
  float gx = g4.x*bneps, gy = g4.y*bneps, gz = g4.z*bneps, gw = g4.w*bneps;
  #pragma unroll
  for (int nt = 0; nt < 8; ++nt){
    s0 += fmaxf(fmaf(acc[nt][0], gx, bb4.x), 0.f);
    s1 += fmaxf(fmaf(acc[nt][1], gy, bb4.y), 0.f);
    s2 += fmaxf(fmaf(acc[nt][2], gz, bb4.z), 0.f);
    s3 += fmaxf(fmaf(acc[nt][3], gw, bb4.w), 0.f);
  }
  #pragma unroll
  for (int off = 1; off < 16; off <<= 1){
    s0 += __shfl_xor(s0, off);
    s1 += __shfl_xor(s1, off);
    s2 += __shfl_xor(s2, off);
    s3 += __shfl_xor(s3, off);
  }
  if (lm == 0){
    float* fa = freq_acc + (size_t)b*C2OUT + octile + lg*4;
    atomicAdd(fa + 0, s0); atomicAdd(fa + 1, s1);
    atomicAdd(fa + 2, s2); atomicAdd(fa + 3, s3);
  }
}

// RGB head + concat + 3-layer MLP, one block per batch sample.
__global__ __launch_bounds__(256) void k_mlp(const float* __restrict__ rgbmean,
    const float* __restrict__ freq_acc, const float* __restrict__ w_rgb,
    const float* __restrict__ b_rgb, const float* __restrict__ fc1w,
    const float* __restrict__ fc1b, const float* __restrict__ fc2w,
    const float* __restrict__ fc2b, const float* __restrict__ fc3w,
    const float* __restrict__ fc3b, float* __restrict__ out){
  __shared__ float z[130], z1[256], z2[128];
  int b = blockIdx.x, t = threadIdx.x;
  if (t < 2){
    float s = b_rgb[t];
    #pragma unroll
    for (int c = 0; c < 3; ++c) s += rgbmean[b*3 + c] * w_rgb[c*2 + t];
    z[t] = s;
  }
  if (t < 128) z[2 + t] = freq_acc[b*C2OUT + t] * (1.f/9216.f);
  __syncthreads();
  { float s = fc1b[t];
    for (int k = 0; k < 130; ++k) s = fmaf(z[k], fc1w[k*256 + t], s);
    z1[t] = fmaxf(s, 0.f); }
  __syncthreads();
  if (t < 128){
    float s = fc2b[t];
    for (int k = 0; k < 256; ++k) s = fmaf(z1[k], fc2w[k*128 + t], s);
    z2[t] = fmaxf(s, 0.f); }
  __syncthreads();
  if (t < 2){
    float s = fc3b[t];
    for (int k = 0; k < 128; ++k) s = fmaf(z2[k], fc3w[k*2 + t], s);
    out[b*2 + t] = s; }
}

extern "C" void kernel_launch(void* const* d_in, const int* in_sizes, int n_in,
                              void* d_out, int out_size, void* d_ws, size_t ws_size,
                              hipStream_t stream){
  const float* x     = (const float*)d_in[0];
  const float* w_rgb = (const float*)d_in[1];
  const float* b_rgb = (const float*)d_in[2];
  const float* w1    = (const float*)d_in[3];
  const float* b1    = (const float*)d_in[4];
  const float* g1    = (const float*)d_in[5];
  const float* bb1   = (const float*)d_in[6];
  const float* w2    = (const float*)d_in[7];
  const float* b2    = (const float*)d_in[8];
  const float* g2    = (const float*)d_in[9];
  const float* bb2   = (const float*)d_in[10];
  const float* fc1w  = (const float*)d_in[11];
  const float* fc1b  = (const float*)d_in[12];
  const float* fc2w  = (const float*)d_in[13];
  const float* fc2b  = (const float*)d_in[14];
  const float* fc3w  = (const float*)d_in[15];
  const float* fc3b  = (const float*)d_in[16];

  const bool full = (ws_size >= NEED_F);
  const int dftloop = full ? 1 : 4;
  const int dftCH   = full ? 96 : 24;
  const int cvloop  = full ? 2 : 16;
  const int cvB     = full ? 16 : 2;

  char* ws = (char*)d_ws;
  float2* T  = (float2*)(ws + OFF_T);
  unsigned short* w1p  = (unsigned short*)(ws + OFF_TW1);
  unsigned short* w2ph = (unsigned short*)(ws + OFF_TW2H);
  float*  Bh   = (float*)(ws + OFF_B);
  float*  col0 = (float*)(ws + OFF_C0);
  unsigned short* P = (unsigned short*)(ws + OFF_P);
  float2* A    = (float2*)(ws + OFF_S);
  unsigned short* E = (unsigned short*)(ws + OFF_S);
  float*  sm = (float*)(ws + (full ? OFF_SM_F : OFF_SM_C));
  float* rgbsum = sm;            // 96
  float* stats  = sm + 96;       // 192
  float* freqa  = sm + 288;      // 4096
  float* rgbm   = sm + 4384;     // 96
  float* ssb    = sm + 4480;     // 192

  hipMemsetAsync(sm, 0, 4672*sizeof(float), stream);
  k_prep<<<288, 256, 0, stream>>>(w1, w2, T, w1p, w2ph);
  for (int c = 0; c < dftloop; ++c){
    k_dft_rows<<<dftCH*48, 192, 0, stream>>>(x, T, A, rgbsum, c*dftCH);
    k_dft_cols<<<dftCH*25, 192, 0, stream>>>(A, T, Bh, col0, stats, c*dftCH);
  }
  k_finalize<<<1, 128, 0, stream>>>(stats, rgbsum, ssb, rgbm);
  for (int c = 0; c < cvloop; ++c){
    k_conv1mfma<<<cvB*144, 256, 0, stream>>>(Bh, col0, ssb, w1p, b1, g1, bb1, E, c*cvB);
    k_pool<<<cvB*288, 256, 0, stream>>>(E, P);
    k_conv2mfma<<<cvB*72, 512, 0, stream>>>(P, w2ph, b2, g2, bb2, freqa, c*cvB);
  }
  k_mlp<<<NB, 256, 0, stream>>>(rgbm, freqa, w_rgb, b_rgb, fc1w, fc1b,
                                fc2w, fc2b, fc3w, fc3b, (float*)d_out);
}